// Round 1
// baseline (2316.039 us; speedup 1.0000x reference)
//
#include <hip/hip_runtime.h>

#define NN 10000
#define NE 320000

typedef __bf16 bf16x8 __attribute__((ext_vector_type(8)));
typedef short  s16x8  __attribute__((ext_vector_type(8)));
typedef float  f32x4  __attribute__((ext_vector_type(4)));

__device__ __forceinline__ unsigned short f2bf(float f) {
  unsigned u = __builtin_bit_cast(unsigned, f);
  u = (u + 0x7FFFu + ((u >> 16) & 1u)) >> 16;
  return (unsigned short)u;
}
__device__ __forceinline__ float bf2f(unsigned short s) {
  unsigned u = ((unsigned)s) << 16;
  return __builtin_bit_cast(float, u);
}
__device__ __forceinline__ float sigm(float x) { return 1.0f / (1.0f + __expf(-x)); }
__device__ __forceinline__ float silu_f(float x) { return x / (1.0f + __expf(-x)); }

// ---------------- prep: transpose weights to bf16 [n][k] layouts ----------------
// We1T: [256][544] (K=528 padded to 544 with zeros)
// We2T: [256][256], Wn1T: [256][512], Wn2T: [256][256]
__global__ void prep_kernel(const float* __restrict__ We1, const float* __restrict__ We2,
                            const float* __restrict__ Wn1, const float* __restrict__ Wn2,
                            unsigned short* __restrict__ We1T, unsigned short* __restrict__ We2T,
                            unsigned short* __restrict__ Wn1T, unsigned short* __restrict__ Wn2T) {
  int g = blockIdx.x * blockDim.x + threadIdx.x;
  const int S1 = 256 * 544, S2 = 256 * 256, S3 = 256 * 512, S4 = 256 * 256;
  if (g < S1) {
    int n = g / 544, k = g % 544;
    float v = (k < 528) ? We1[k * 256 + n] : 0.0f;
    We1T[g] = f2bf(v);
  } else if (g < S1 + S2) {
    int i = g - S1; int n = i >> 8, k = i & 255;
    We2T[i] = f2bf(We2[k * 256 + n]);
  } else if (g < S1 + S2 + S3) {
    int i = g - S1 - S2; int n = i >> 9, k = i & 511;
    Wn1T[i] = f2bf(Wn1[k * 256 + n]);
  } else if (g < S1 + S2 + S3 + S4) {
    int i = g - S1 - S2 - S3; int n = i >> 8, k = i & 255;
    Wn2T[i] = f2bf(Wn2[k * 256 + n]);
  }
}

// ---------------- edge kernel: fused edge MLP + att + mij write + agg atomics ----
// block: 512 threads (8 waves, 2x4), tile 128 edges x 256 cols
__global__ __launch_bounds__(512) void edge_kernel(
    const float* __restrict__ h, const int* __restrict__ eidx,
    const float* __restrict__ eattr, const float* __restrict__ emask,
    const unsigned short* __restrict__ We1T, const float* __restrict__ be1,
    const unsigned short* __restrict__ We2T, const float* __restrict__ be2,
    const float* __restrict__ Wa, const float* __restrict__ ba,
    float* __restrict__ mij_out, float* __restrict__ agg) {
  // LDS: padded strides keep ds_read_b128 bank conflicts at free 2-way
  __shared__ unsigned short Abuf[128 * 40];   // [128][32] pad->40
  __shared__ unsigned short Bbuf[256 * 40];   // [256][32] pad->40
  __shared__ unsigned short A2[128 * 264];    // [128][256] pad->264
  __shared__ int rowL[128], colL[128];
  __shared__ float emaskL[128], attL[128];
  __shared__ float waL[256], be1L[256], be2L[256];

  const int tid = threadIdx.x;
  const int lane = tid & 63;
  const int wid = tid >> 6;
  const int wr = wid >> 2, wc = wid & 3;
  const int e0 = blockIdx.x * 128;

  // detect int64 vs int32 edge_index: int64 hi-words (odd int32 slots) are all 0
  bool is64 = true;
  {
    #pragma unroll
    for (int i = 1; i < 64; i += 2) is64 = is64 && (eidx[i] == 0);
  }

  if (tid < 128) {
    if (is64) {
      const long long* p64 = (const long long*)eidx;
      rowL[tid] = (int)p64[e0 + tid];
      colL[tid] = (int)p64[NE + e0 + tid];
    } else {
      rowL[tid] = eidx[e0 + tid];
      colL[tid] = eidx[NE + e0 + tid];
    }
    emaskL[tid] = emask[e0 + tid];
  }
  if (tid >= 256) {
    int i = tid - 256;
    waL[i] = Wa[i]; be1L[i] = be1[i]; be2L[i] = be2[i];
  }

  f32x4 acc[4][4];
  #pragma unroll
  for (int m = 0; m < 4; m++)
    #pragma unroll
    for (int n = 0; n < 4; n++) acc[m][n] = (f32x4){0.f, 0.f, 0.f, 0.f};

  const int eA = tid >> 2, sA = tid & 3;       // A staging: 8 elems/thread
  const int rbase = (wr << 6) + (lane & 15);
  const int koff = (lane >> 4) << 3;
  const int cfrag = lane & 15;

  // ---------------- layer 1: K = 528 (17 tiles of 32, last zero-padded) --------
  for (int kt = 0; kt < 17; ++kt) {
    const int k0 = kt << 5;
    __syncthreads();
    { // stage A (gather h[row], h[col], edge_attr; convert fp32->bf16)
      s16x8 v;
      if (k0 < 512) {
        int node = (k0 < 256) ? rowL[eA] : colL[eA];
        const float* src = h + node * 256 + (k0 & 255) + (sA << 3);
        float4 f0 = *(const float4*)src;
        float4 f1 = *(const float4*)(src + 4);
        v[0] = (short)f2bf(f0.x); v[1] = (short)f2bf(f0.y);
        v[2] = (short)f2bf(f0.z); v[3] = (short)f2bf(f0.w);
        v[4] = (short)f2bf(f1.x); v[5] = (short)f2bf(f1.y);
        v[6] = (short)f2bf(f1.z); v[7] = (short)f2bf(f1.w);
      } else if (sA < 2) {
        const float* src = eattr + eA * 16 + (sA << 3);
        float4 f0 = *(const float4*)src;
        float4 f1 = *(const float4*)(src + 4);
        v[0] = (short)f2bf(f0.x); v[1] = (short)f2bf(f0.y);
        v[2] = (short)f2bf(f0.z); v[3] = (short)f2bf(f0.w);
        v[4] = (short)f2bf(f1.x); v[5] = (short)f2bf(f1.y);
        v[6] = (short)f2bf(f1.z); v[7] = (short)f2bf(f1.w);
      } else {
        v = (s16x8){0, 0, 0, 0, 0, 0, 0, 0};
      }
      *(s16x8*)&Abuf[eA * 40 + (sA << 3)] = v;
    }
    // stage B from We1T (bf16 already)
    #pragma unroll
    for (int i = 0; i < 2; ++i) {
      int idx = tid + (i << 9);
      int n = idx >> 2, s = idx & 3;
      s16x8 v = *(const s16x8*)(We1T + n * 544 + k0 + (s << 3));
      *(s16x8*)&Bbuf[n * 40 + (s << 3)] = v;
    }
    __syncthreads();
    bf16x8 a[4], b[4];
    #pragma unroll
    for (int m = 0; m < 4; m++)
      a[m] = __builtin_bit_cast(bf16x8, *(const s16x8*)&Abuf[(rbase + m * 16) * 40 + koff]);
    #pragma unroll
    for (int n = 0; n < 4; n++)
      b[n] = __builtin_bit_cast(bf16x8, *(const s16x8*)&Bbuf[((wc << 6) + n * 16 + cfrag) * 40 + koff]);
    #pragma unroll
    for (int m = 0; m < 4; m++)
      #pragma unroll
      for (int n = 0; n < 4; n++)
        acc[m][n] = __builtin_amdgcn_mfma_f32_16x16x32_bf16(a[m], b[n], acc[m][n], 0, 0, 0);
  }

  // bias + SiLU -> A2 (bf16)
  #pragma unroll
  for (int m = 0; m < 4; m++) {
    int rl = (wr << 6) + m * 16 + ((lane >> 4) << 2);
    #pragma unroll
    for (int n = 0; n < 4; n++) {
      int cg = (wc << 6) + n * 16 + cfrag;
      float bias = be1L[cg];
      #pragma unroll
      for (int j = 0; j < 4; j++) {
        float x = acc[m][n][j] + bias;
        A2[(rl + j) * 264 + cg] = f2bf(silu_f(x));
      }
      acc[m][n] = (f32x4){0.f, 0.f, 0.f, 0.f};
    }
  }

  // ---------------- layer 2: K = 256 (8 tiles) --------------------------------
  for (int kt = 0; kt < 8; ++kt) {
    const int k0 = kt << 5;
    __syncthreads();
    #pragma unroll
    for (int i = 0; i < 2; ++i) {
      int idx = tid + (i << 9);
      int n = idx >> 2, s = idx & 3;
      s16x8 v = *(const s16x8*)(We2T + (n << 8) + k0 + (s << 3));
      *(s16x8*)&Bbuf[n * 40 + (s << 3)] = v;
    }
    __syncthreads();
    bf16x8 a[4], b[4];
    #pragma unroll
    for (int m = 0; m < 4; m++)
      a[m] = __builtin_bit_cast(bf16x8, *(const s16x8*)&A2[(rbase + m * 16) * 264 + k0 + koff]);
    #pragma unroll
    for (int n = 0; n < 4; n++)
      b[n] = __builtin_bit_cast(bf16x8, *(const s16x8*)&Bbuf[((wc << 6) + n * 16 + cfrag) * 40 + koff]);
    #pragma unroll
    for (int m = 0; m < 4; m++)
      #pragma unroll
      for (int n = 0; n < 4; n++)
        acc[m][n] = __builtin_amdgcn_mfma_f32_16x16x32_bf16(a[m], b[n], acc[m][n], 0, 0, 0);
  }

  // mij = silu(acc + be2) -> A2 (all A2 reads done; barrier then overwrite)
  __syncthreads();
  #pragma unroll
  for (int m = 0; m < 4; m++) {
    int rl = (wr << 6) + m * 16 + ((lane >> 4) << 2);
    #pragma unroll
    for (int n = 0; n < 4; n++) {
      int cg = (wc << 6) + n * 16 + cfrag;
      float bias = be2L[cg];
      #pragma unroll
      for (int j = 0; j < 4; j++) {
        float x = acc[m][n][j] + bias;
        A2[(rl + j) * 264 + cg] = f2bf(silu_f(x));
      }
    }
  }
  __syncthreads();

  // attention: 4 threads per edge, each 64-elem partial dot, shfl reduce
  {
    int e = tid >> 2, part = tid & 3;
    float s = 0.f;
    const unsigned short* mrow = &A2[e * 264 + (part << 6)];
    #pragma unroll
    for (int kk = 0; kk < 8; ++kk) {
      s16x8 v = *(const s16x8*)(mrow + (kk << 3));
      #pragma unroll
      for (int j = 0; j < 8; j++)
        s += bf2f((unsigned short)v[j]) * waL[(part << 6) + (kk << 3) + j];
    }
    s += __shfl_xor(s, 1);
    s += __shfl_xor(s, 2);
    if (part == 0) attL[e] = sigm(s + ba[0]);
  }
  __syncthreads();

  // write mij (fp32, coalesced) + scatter-add edge_feat into agg
  #pragma unroll
  for (int i = 0; i < 8; ++i) {
    int idx = tid + (i << 9);
    int e = idx >> 5;
    int c8 = (idx & 31) << 3;
    s16x8 v = *(const s16x8*)&A2[e * 264 + c8];
    float f[8];
    #pragma unroll
    for (int j = 0; j < 8; j++) f[j] = bf2f((unsigned short)v[j]);
    float* dst = mij_out + (size_t)(e0 + e) * 256 + c8;
    *(float4*)dst = (float4){f[0], f[1], f[2], f[3]};
    *(float4*)(dst + 4) = (float4){f[4], f[5], f[6], f[7]};
    float am = attL[e] * emaskL[e];
    float* ag = agg + (size_t)rowL[e] * 256 + c8;
    #pragma unroll
    for (int j = 0; j < 8; j++) atomicAdd(ag + j, f[j] * am);
  }
}

// ---------------- node kernel: h_out = h + MLP([h, agg/32]) -------------------
__global__ __launch_bounds__(512) void node_kernel(
    const float* __restrict__ h, const float* __restrict__ agg,
    const float* __restrict__ nmask,
    const unsigned short* __restrict__ Wn1T, const float* __restrict__ bn1,
    const unsigned short* __restrict__ Wn2T, const float* __restrict__ bn2,
    float* __restrict__ hout) {
  __shared__ unsigned short Abuf[128 * 40];
  __shared__ unsigned short Bbuf[256 * 40];
  __shared__ unsigned short A2[128 * 264];
  __shared__ float bn1L[256], bn2L[256];

  const int tid = threadIdx.x;
  const int lane = tid & 63;
  const int wid = tid >> 6;
  const int wr = wid >> 2, wc = wid & 3;
  const int n0 = blockIdx.x * 128;

  if (tid < 256) { bn1L[tid] = bn1[tid]; bn2L[tid] = bn2[tid]; }

  f32x4 acc[4][4];
  #pragma unroll
  for (int m = 0; m < 4; m++)
    #pragma unroll
    for (int n = 0; n < 4; n++) acc[m][n] = (f32x4){0.f, 0.f, 0.f, 0.f};

  const int eA = tid >> 2, sA = tid & 3;
  int nodeA = n0 + eA; if (nodeA >= NN) nodeA = NN - 1;  // clamp tail loads
  const int rbase = (wr << 6) + (lane & 15);
  const int koff = (lane >> 4) << 3;
  const int cfrag = lane & 15;

  // layer 1: K = 512 (16 tiles): k<256 -> h, k>=256 -> agg/32
  for (int kt = 0; kt < 16; ++kt) {
    const int k0 = kt << 5;
    __syncthreads();
    {
      const float* src = (k0 < 256) ? (h + nodeA * 256 + k0 + (sA << 3))
                                    : (agg + nodeA * 256 + (k0 - 256) + (sA << 3));
      const float sc = (k0 < 256) ? 1.0f : (1.0f / 32.0f);
      float4 f0 = *(const float4*)src;
      float4 f1 = *(const float4*)(src + 4);
      s16x8 v;
      v[0] = (short)f2bf(f0.x * sc); v[1] = (short)f2bf(f0.y * sc);
      v[2] = (short)f2bf(f0.z * sc); v[3] = (short)f2bf(f0.w * sc);
      v[4] = (short)f2bf(f1.x * sc); v[5] = (short)f2bf(f1.y * sc);
      v[6] = (short)f2bf(f1.z * sc); v[7] = (short)f2bf(f1.w * sc);
      *(s16x8*)&Abuf[eA * 40 + (sA << 3)] = v;
    }
    #pragma unroll
    for (int i = 0; i < 2; ++i) {
      int idx = tid + (i << 9);
      int n = idx >> 2, s = idx & 3;
      s16x8 v = *(const s16x8*)(Wn1T + (n << 9) + k0 + (s << 3));
      *(s16x8*)&Bbuf[n * 40 + (s << 3)] = v;
    }
    __syncthreads();
    bf16x8 a[4], b[4];
    #pragma unroll
    for (int m = 0; m < 4; m++)
      a[m] = __builtin_bit_cast(bf16x8, *(const s16x8*)&Abuf[(rbase + m * 16) * 40 + koff]);
    #pragma unroll
    for (int n = 0; n < 4; n++)
      b[n] = __builtin_bit_cast(bf16x8, *(const s16x8*)&Bbuf[((wc << 6) + n * 16 + cfrag) * 40 + koff]);
    #pragma unroll
    for (int m = 0; m < 4; m++)
      #pragma unroll
      for (int n = 0; n < 4; n++)
        acc[m][n] = __builtin_amdgcn_mfma_f32_16x16x32_bf16(a[m], b[n], acc[m][n], 0, 0, 0);
  }

  #pragma unroll
  for (int m = 0; m < 4; m++) {
    int rl = (wr << 6) + m * 16 + ((lane >> 4) << 2);
    #pragma unroll
    for (int n = 0; n < 4; n++) {
      int cg = (wc << 6) + n * 16 + cfrag;
      float bias = bn1L[cg];
      #pragma unroll
      for (int j = 0; j < 4; j++) {
        float x = acc[m][n][j] + bias;
        A2[(rl + j) * 264 + cg] = f2bf(silu_f(x));
      }
      acc[m][n] = (f32x4){0.f, 0.f, 0.f, 0.f};
    }
  }

  // layer 2: K = 256
  for (int kt = 0; kt < 8; ++kt) {
    const int k0 = kt << 5;
    __syncthreads();
    #pragma unroll
    for (int i = 0; i < 2; ++i) {
      int idx = tid + (i << 9);
      int n = idx >> 2, s = idx & 3;
      s16x8 v = *(const s16x8*)(Wn2T + (n << 8) + k0 + (s << 3));
      *(s16x8*)&Bbuf[n * 40 + (s << 3)] = v;
    }
    __syncthreads();
    bf16x8 a[4], b[4];
    #pragma unroll
    for (int m = 0; m < 4; m++)
      a[m] = __builtin_bit_cast(bf16x8, *(const s16x8*)&A2[(rbase + m * 16) * 264 + k0 + koff]);
    #pragma unroll
    for (int n = 0; n < 4; n++)
      b[n] = __builtin_bit_cast(bf16x8, *(const s16x8*)&Bbuf[((wc << 6) + n * 16 + cfrag) * 40 + koff]);
    #pragma unroll
    for (int m = 0; m < 4; m++)
      #pragma unroll
      for (int n = 0; n < 4; n++)
        acc[m][n] = __builtin_amdgcn_mfma_f32_16x16x32_bf16(a[m], b[n], acc[m][n], 0, 0, 0);
  }

  // epilogue: out = (h + acc + bn2) * node_mask
  #pragma unroll
  for (int m = 0; m < 4; m++) {
    int rl = (wr << 6) + m * 16 + ((lane >> 4) << 2);
    #pragma unroll
    for (int n = 0; n < 4; n++) {
      int cg = (wc << 6) + n * 16 + cfrag;
      #pragma unroll
      for (int j = 0; j < 4; j++) {
        int rg = n0 + rl + j;
        if (rg < NN) {
          float val = acc[m][n][j] + bn2L[cg];
          float o = (h[(size_t)rg * 256 + cg] + val) * nmask[rg];
          hout[(size_t)rg * 256 + cg] = o;
        }
      }
    }
  }
}

extern "C" void kernel_launch(void* const* d_in, const int* in_sizes, int n_in,
                              void* d_out, int out_size, void* d_ws, size_t ws_size,
                              hipStream_t stream) {
  (void)in_sizes; (void)n_in; (void)out_size; (void)ws_size;
  const float* h     = (const float*)d_in[0];
  const int*   eidx  = (const int*)d_in[1];
  const float* eattr = (const float*)d_in[2];
  const float* nmask = (const float*)d_in[3];
  const float* emask = (const float*)d_in[4];
  const float* We1 = (const float*)d_in[5];
  const float* be1 = (const float*)d_in[6];
  const float* We2 = (const float*)d_in[7];
  const float* be2 = (const float*)d_in[8];
  const float* Wa  = (const float*)d_in[9];
  const float* ba  = (const float*)d_in[10];
  const float* Wn1 = (const float*)d_in[11];
  const float* bn1 = (const float*)d_in[12];
  const float* Wn2 = (const float*)d_in[13];
  const float* bn2 = (const float*)d_in[14];

  char* ws = (char*)d_ws;
  unsigned short* We1T = (unsigned short*)(ws + 0);        // 256*544*2 = 278528
  unsigned short* We2T = (unsigned short*)(ws + 278528);   // 131072
  unsigned short* Wn1T = (unsigned short*)(ws + 409600);   // 262144
  unsigned short* Wn2T = (unsigned short*)(ws + 671744);   // 131072
  float*          agg  = (float*)(ws + 802816);            // 10,240,000 bytes

  float* hout = (float*)d_out;
  float* mij  = (float*)d_out + (size_t)NN * 256;

  hipMemsetAsync(agg, 0, (size_t)NN * 256 * sizeof(float), stream);
  prep_kernel<<<1568, 256, 0, stream>>>(We1, We2, Wn1, Wn2, We1T, We2T, Wn1T, Wn2T);
  edge_kernel<<<NE / 128, 512, 0, stream>>>(h, eidx, eattr, emask, We1T, be1, We2T, be2,
                                            Wa, ba, mij, agg);
  node_kernel<<<(NN + 127) / 128, 512, 0, stream>>>(h, agg, nmask, Wn1T, bn1, Wn2T, bn2, hout);
}

// Round 2
// 577.348 us; speedup vs baseline: 4.0115x; 4.0115x over previous
//
#include <hip/hip_runtime.h>

#define NN 10000
#define NE 320000

typedef __bf16 bf16x8 __attribute__((ext_vector_type(8)));
typedef short  s16x8  __attribute__((ext_vector_type(8)));
typedef float  f32x4  __attribute__((ext_vector_type(4)));

__device__ __forceinline__ unsigned short f2bf(float f) {
  unsigned u = __builtin_bit_cast(unsigned, f);
  u = (u + 0x7FFFu + ((u >> 16) & 1u)) >> 16;
  return (unsigned short)u;
}
__device__ __forceinline__ float bf2f(unsigned short s) {
  unsigned u = ((unsigned)s) << 16;
  return __builtin_bit_cast(float, u);
}
__device__ __forceinline__ float sigm(float x) { return 1.0f / (1.0f + __expf(-x)); }
__device__ __forceinline__ float silu_f(float x) { return x / (1.0f + __expf(-x)); }

// ---------------- prep: transpose weights to bf16 [n][k] layouts ----------------
__global__ void prep_kernel(const float* __restrict__ We1, const float* __restrict__ We2,
                            const float* __restrict__ Wn1, const float* __restrict__ Wn2,
                            unsigned short* __restrict__ We1T, unsigned short* __restrict__ We2T,
                            unsigned short* __restrict__ Wn1T, unsigned short* __restrict__ Wn2T) {
  int g = blockIdx.x * blockDim.x + threadIdx.x;
  const int S1 = 256 * 544, S2 = 256 * 256, S3 = 256 * 512, S4 = 256 * 256;
  if (g < S1) {
    int n = g / 544, k = g % 544;
    float v = (k < 528) ? We1[k * 256 + n] : 0.0f;
    We1T[g] = f2bf(v);
  } else if (g < S1 + S2) {
    int i = g - S1; int n = i >> 8, k = i & 255;
    We2T[i] = f2bf(We2[k * 256 + n]);
  } else if (g < S1 + S2 + S3) {
    int i = g - S1 - S2; int n = i >> 9, k = i & 511;
    Wn1T[i] = f2bf(Wn1[k * 256 + n]);
  } else if (g < S1 + S2 + S3 + S4) {
    int i = g - S1 - S2 - S3; int n = i >> 8, k = i & 255;
    Wn2T[i] = f2bf(Wn2[k * 256 + n]);
  }
}

// ---------------- CSR build: histogram -> scan -> scatter ----------------------
__global__ void hist_kernel(const int* __restrict__ eidx, int* __restrict__ rowi,
                            int* __restrict__ counts) {
  __shared__ int s64;
  if (threadIdx.x == 0) {
    bool b = true;
    for (int i = 1; i < 64; i += 2) b = b && (eidx[i] == 0);
    s64 = b ? 1 : 0;
  }
  __syncthreads();
  int e = blockIdx.x * 256 + threadIdx.x;
  if (e < NE) {
    int r = s64 ? (int)((const long long*)eidx)[e] : eidx[e];
    rowi[e] = r;
    atomicAdd(&counts[r], 1);
  }
}

__global__ __launch_bounds__(1024) void scan_kernel(const int* __restrict__ counts,
                                                    int* __restrict__ rowStart,
                                                    int* __restrict__ cursor) {
  __shared__ int part[1024];
  int t = threadIdx.x;
  int local[10];
  int s = 0;
  #pragma unroll
  for (int i = 0; i < 10; i++) {
    int idx = t * 10 + i;
    int c = (idx < NN) ? counts[idx] : 0;
    local[i] = s; s += c;
  }
  part[t] = s;
  __syncthreads();
  int val = s;
  for (int off = 1; off < 1024; off <<= 1) {
    int tmp = (t >= off) ? part[t - off] : 0;
    __syncthreads();
    part[t] += tmp;
    __syncthreads();
  }
  int base = part[t] - val;  // exclusive
  #pragma unroll
  for (int i = 0; i < 10; i++) {
    int idx = t * 10 + i;
    if (idx < NN) { int v = base + local[i]; rowStart[idx] = v; cursor[idx] = v; }
  }
  if (t == 1023) rowStart[NN] = NE;
}

__global__ void scatter_kernel(const int* __restrict__ rowi, int* __restrict__ cursor,
                               int* __restrict__ eorder) {
  int e = blockIdx.x * 256 + threadIdx.x;
  if (e < NE) {
    int pos = atomicAdd(&cursor[rowi[e]], 1);
    eorder[pos] = e;
  }
}

// ---------------- edge kernel: fused edge MLP + att; NO atomics ---------------
__global__ __launch_bounds__(512) void edge_kernel(
    const float* __restrict__ h, const int* __restrict__ eidx,
    const float* __restrict__ eattr, const float* __restrict__ emask,
    const unsigned short* __restrict__ We1T, const float* __restrict__ be1,
    const unsigned short* __restrict__ We2T, const float* __restrict__ be2,
    const float* __restrict__ Wa, const float* __restrict__ ba,
    float* __restrict__ mij_out, float* __restrict__ attm) {
  __shared__ unsigned short Abuf[128 * 40];   // [128][32] pad->40
  __shared__ unsigned short Bbuf[256 * 40];   // [256][32] pad->40
  __shared__ unsigned short A2[128 * 264];    // [128][256] pad->264
  __shared__ int rowL[128], colL[128];
  __shared__ float waL[256], be1L[256], be2L[256];
  __shared__ int s64;

  const int tid = threadIdx.x;
  const int lane = tid & 63;
  const int wid = tid >> 6;
  const int wr = wid >> 2, wc = wid & 3;
  const int e0 = blockIdx.x * 128;

  if (tid == 0) {
    bool b = true;
    for (int i = 1; i < 64; i += 2) b = b && (eidx[i] == 0);
    s64 = b ? 1 : 0;
  }
  __syncthreads();

  if (tid < 128) {
    if (s64) {
      const long long* p64 = (const long long*)eidx;
      rowL[tid] = (int)p64[e0 + tid];
      colL[tid] = (int)p64[NE + e0 + tid];
    } else {
      rowL[tid] = eidx[e0 + tid];
      colL[tid] = eidx[NE + e0 + tid];
    }
  }
  if (tid >= 256) {
    int i = tid - 256;
    waL[i] = Wa[i]; be1L[i] = be1[i]; be2L[i] = be2[i];
  }

  f32x4 acc[4][4];
  #pragma unroll
  for (int m = 0; m < 4; m++)
    #pragma unroll
    for (int n = 0; n < 4; n++) acc[m][n] = (f32x4){0.f, 0.f, 0.f, 0.f};

  const int eA = tid >> 2, sA = tid & 3;
  const int rbase = (wr << 6) + (lane & 15);
  const int koff = (lane >> 4) << 3;
  const int cfrag = lane & 15;

  // ---------------- layer 1: K = 528 (17 tiles of 32) -------------------------
  for (int kt = 0; kt < 17; ++kt) {
    const int k0 = kt << 5;
    __syncthreads();
    {
      s16x8 v;
      if (k0 < 512) {
        int node = (k0 < 256) ? rowL[eA] : colL[eA];
        const float* src = h + node * 256 + (k0 & 255) + (sA << 3);
        float4 f0 = *(const float4*)src;
        float4 f1 = *(const float4*)(src + 4);
        v[0] = (short)f2bf(f0.x); v[1] = (short)f2bf(f0.y);
        v[2] = (short)f2bf(f0.z); v[3] = (short)f2bf(f0.w);
        v[4] = (short)f2bf(f1.x); v[5] = (short)f2bf(f1.y);
        v[6] = (short)f2bf(f1.z); v[7] = (short)f2bf(f1.w);
      } else if (sA < 2) {
        const float* src = eattr + eA * 16 + (sA << 3);
        float4 f0 = *(const float4*)src;
        float4 f1 = *(const float4*)(src + 4);
        v[0] = (short)f2bf(f0.x); v[1] = (short)f2bf(f0.y);
        v[2] = (short)f2bf(f0.z); v[3] = (short)f2bf(f0.w);
        v[4] = (short)f2bf(f1.x); v[5] = (short)f2bf(f1.y);
        v[6] = (short)f2bf(f1.z); v[7] = (short)f2bf(f1.w);
      } else {
        v = (s16x8){0, 0, 0, 0, 0, 0, 0, 0};
      }
      *(s16x8*)&Abuf[eA * 40 + (sA << 3)] = v;
    }
    #pragma unroll
    for (int i = 0; i < 2; ++i) {
      int idx = tid + (i << 9);
      int n = idx >> 2, s = idx & 3;
      s16x8 v = *(const s16x8*)(We1T + n * 544 + k0 + (s << 3));
      *(s16x8*)&Bbuf[n * 40 + (s << 3)] = v;
    }
    __syncthreads();
    bf16x8 a[4], b[4];
    #pragma unroll
    for (int m = 0; m < 4; m++)
      a[m] = __builtin_bit_cast(bf16x8, *(const s16x8*)&Abuf[(rbase + m * 16) * 40 + koff]);
    #pragma unroll
    for (int n = 0; n < 4; n++)
      b[n] = __builtin_bit_cast(bf16x8, *(const s16x8*)&Bbuf[((wc << 6) + n * 16 + cfrag) * 40 + koff]);
    #pragma unroll
    for (int m = 0; m < 4; m++)
      #pragma unroll
      for (int n = 0; n < 4; n++)
        acc[m][n] = __builtin_amdgcn_mfma_f32_16x16x32_bf16(a[m], b[n], acc[m][n], 0, 0, 0);
  }

  // bias + SiLU -> A2 (bf16)
  #pragma unroll
  for (int m = 0; m < 4; m++) {
    int rl = (wr << 6) + m * 16 + ((lane >> 4) << 2);
    #pragma unroll
    for (int n = 0; n < 4; n++) {
      int cg = (wc << 6) + n * 16 + cfrag;
      float bias = be1L[cg];
      #pragma unroll
      for (int j = 0; j < 4; j++) {
        float x = acc[m][n][j] + bias;
        A2[(rl + j) * 264 + cg] = f2bf(silu_f(x));
      }
      acc[m][n] = (f32x4){0.f, 0.f, 0.f, 0.f};
    }
  }

  // ---------------- layer 2: K = 256 (8 tiles) --------------------------------
  for (int kt = 0; kt < 8; ++kt) {
    const int k0 = kt << 5;
    __syncthreads();
    #pragma unroll
    for (int i = 0; i < 2; ++i) {
      int idx = tid + (i << 9);
      int n = idx >> 2, s = idx & 3;
      s16x8 v = *(const s16x8*)(We2T + (n << 8) + k0 + (s << 3));
      *(s16x8*)&Bbuf[n * 40 + (s << 3)] = v;
    }
    __syncthreads();
    bf16x8 a[4], b[4];
    #pragma unroll
    for (int m = 0; m < 4; m++)
      a[m] = __builtin_bit_cast(bf16x8, *(const s16x8*)&A2[(rbase + m * 16) * 264 + k0 + koff]);
    #pragma unroll
    for (int n = 0; n < 4; n++)
      b[n] = __builtin_bit_cast(bf16x8, *(const s16x8*)&Bbuf[((wc << 6) + n * 16 + cfrag) * 40 + koff]);
    #pragma unroll
    for (int m = 0; m < 4; m++)
      #pragma unroll
      for (int n = 0; n < 4; n++)
        acc[m][n] = __builtin_amdgcn_mfma_f32_16x16x32_bf16(a[m], b[n], acc[m][n], 0, 0, 0);
  }

  // mij = silu(acc + be2): write fp32 DIRECTLY to global (accuracy + no extra pass),
  // and bf16 copy into A2 for the attention dot.
  __syncthreads();  // all layer-2 A2 reads done
  #pragma unroll
  for (int m = 0; m < 4; m++) {
    int rl = (wr << 6) + m * 16 + ((lane >> 4) << 2);
    #pragma unroll
    for (int n = 0; n < 4; n++) {
      int cg = (wc << 6) + n * 16 + cfrag;
      float bias = be2L[cg];
      #pragma unroll
      for (int j = 0; j < 4; j++) {
        float x = silu_f(acc[m][n][j] + bias);
        A2[(rl + j) * 264 + cg] = f2bf(x);
        mij_out[(size_t)(e0 + rl + j) * 256 + cg] = x;
      }
    }
  }
  __syncthreads();

  // attention: 4 threads per edge, 64-elem partial dots, shfl reduce; write att*emask
  {
    int e = tid >> 2, part = tid & 3;
    float s = 0.f;
    const unsigned short* mrow = &A2[e * 264 + (part << 6)];
    #pragma unroll
    for (int kk = 0; kk < 8; ++kk) {
      s16x8 v = *(const s16x8*)(mrow + (kk << 3));
      #pragma unroll
      for (int j = 0; j < 8; j++)
        s += bf2f((unsigned short)v[j]) * waL[(part << 6) + (kk << 3) + j];
    }
    s += __shfl_xor(s, 1);
    s += __shfl_xor(s, 2);
    if (part == 0) attm[e0 + e] = sigm(s + ba[0]) * emask[e0 + e];
  }
}

// ---------------- aggregation: CSR gather, no atomics -------------------------
__global__ __launch_bounds__(256) void agg_kernel(
    const float* __restrict__ mij, const float* __restrict__ attm,
    const int* __restrict__ rowStart, const int* __restrict__ eorder,
    float* __restrict__ agg) {
  int n = blockIdx.x;
  int t = threadIdx.x;
  int start = rowStart[n], end = rowStart[n + 1];
  float s = 0.f;
  int i = start;
  for (; i + 4 <= end; i += 4) {
    int ea = eorder[i], eb = eorder[i + 1], ec = eorder[i + 2], ed = eorder[i + 3];
    float aa = attm[ea], ab = attm[eb], ac = attm[ec], ad = attm[ed];
    s += mij[(size_t)ea * 256 + t] * aa;
    s += mij[(size_t)eb * 256 + t] * ab;
    s += mij[(size_t)ec * 256 + t] * ac;
    s += mij[(size_t)ed * 256 + t] * ad;
  }
  for (; i < end; ++i) {
    int e = eorder[i];
    s += mij[(size_t)e * 256 + t] * attm[e];
  }
  agg[(size_t)n * 256 + t] = s;
}

// ---------------- node kernel: h_out = h + MLP([h, agg/32]) -------------------
__global__ __launch_bounds__(512) void node_kernel(
    const float* __restrict__ h, const float* __restrict__ agg,
    const float* __restrict__ nmask,
    const unsigned short* __restrict__ Wn1T, const float* __restrict__ bn1,
    const unsigned short* __restrict__ Wn2T, const float* __restrict__ bn2,
    float* __restrict__ hout) {
  __shared__ unsigned short Abuf[128 * 40];
  __shared__ unsigned short Bbuf[256 * 40];
  __shared__ unsigned short A2[128 * 264];
  __shared__ float bn1L[256], bn2L[256];

  const int tid = threadIdx.x;
  const int lane = tid & 63;
  const int wid = tid >> 6;
  const int wr = wid >> 2, wc = wid & 3;
  const int n0 = blockIdx.x * 128;

  if (tid < 256) { bn1L[tid] = bn1[tid]; bn2L[tid] = bn2[tid]; }

  f32x4 acc[4][4];
  #pragma unroll
  for (int m = 0; m < 4; m++)
    #pragma unroll
    for (int n = 0; n < 4; n++) acc[m][n] = (f32x4){0.f, 0.f, 0.f, 0.f};

  const int eA = tid >> 2, sA = tid & 3;
  int nodeA = n0 + eA; if (nodeA >= NN) nodeA = NN - 1;
  const int rbase = (wr << 6) + (lane & 15);
  const int koff = (lane >> 4) << 3;
  const int cfrag = lane & 15;

  for (int kt = 0; kt < 16; ++kt) {
    const int k0 = kt << 5;
    __syncthreads();
    {
      const float* src = (k0 < 256) ? (h + nodeA * 256 + k0 + (sA << 3))
                                    : (agg + nodeA * 256 + (k0 - 256) + (sA << 3));
      const float sc = (k0 < 256) ? 1.0f : (1.0f / 32.0f);
      float4 f0 = *(const float4*)src;
      float4 f1 = *(const float4*)(src + 4);
      s16x8 v;
      v[0] = (short)f2bf(f0.x * sc); v[1] = (short)f2bf(f0.y * sc);
      v[2] = (short)f2bf(f0.z * sc); v[3] = (short)f2bf(f0.w * sc);
      v[4] = (short)f2bf(f1.x * sc); v[5] = (short)f2bf(f1.y * sc);
      v[6] = (short)f2bf(f1.z * sc); v[7] = (short)f2bf(f1.w * sc);
      *(s16x8*)&Abuf[eA * 40 + (sA << 3)] = v;
    }
    #pragma unroll
    for (int i = 0; i < 2; ++i) {
      int idx = tid + (i << 9);
      int n = idx >> 2, s = idx & 3;
      s16x8 v = *(const s16x8*)(Wn1T + (n << 9) + k0 + (s << 3));
      *(s16x8*)&Bbuf[n * 40 + (s << 3)] = v;
    }
    __syncthreads();
    bf16x8 a[4], b[4];
    #pragma unroll
    for (int m = 0; m < 4; m++)
      a[m] = __builtin_bit_cast(bf16x8, *(const s16x8*)&Abuf[(rbase + m * 16) * 40 + koff]);
    #pragma unroll
    for (int n = 0; n < 4; n++)
      b[n] = __builtin_bit_cast(bf16x8, *(const s16x8*)&Bbuf[((wc << 6) + n * 16 + cfrag) * 40 + koff]);
    #pragma unroll
    for (int m = 0; m < 4; m++)
      #pragma unroll
      for (int n = 0; n < 4; n++)
        acc[m][n] = __builtin_amdgcn_mfma_f32_16x16x32_bf16(a[m], b[n], acc[m][n], 0, 0, 0);
  }

  #pragma unroll
  for (int m = 0; m < 4; m++) {
    int rl = (wr << 6) + m * 16 + ((lane >> 4) << 2);
    #pragma unroll
    for (int n = 0; n < 4; n++) {
      int cg = (wc << 6) + n * 16 + cfrag;
      float bias = bn1L[cg];
      #pragma unroll
      for (int j = 0; j < 4; j++) {
        float x = acc[m][n][j] + bias;
        A2[(rl + j) * 264 + cg] = f2bf(silu_f(x));
      }
      acc[m][n] = (f32x4){0.f, 0.f, 0.f, 0.f};
    }
  }

  for (int kt = 0; kt < 8; ++kt) {
    const int k0 = kt << 5;
    __syncthreads();
    #pragma unroll
    for (int i = 0; i < 2; ++i) {
      int idx = tid + (i << 9);
      int n = idx >> 2, s = idx & 3;
      s16x8 v = *(const s16x8*)(Wn2T + (n << 8) + k0 + (s << 3));
      *(s16x8*)&Bbuf[n * 40 + (s << 3)] = v;
    }
    __syncthreads();
    bf16x8 a[4], b[4];
    #pragma unroll
    for (int m = 0; m < 4; m++)
      a[m] = __builtin_bit_cast(bf16x8, *(const s16x8*)&A2[(rbase + m * 16) * 264 + k0 + koff]);
    #pragma unroll
    for (int n = 0; n < 4; n++)
      b[n] = __builtin_bit_cast(bf16x8, *(const s16x8*)&Bbuf[((wc << 6) + n * 16 + cfrag) * 40 + koff]);
    #pragma unroll
    for (int m = 0; m < 4; m++)
      #pragma unroll
      for (int n = 0; n < 4; n++)
        acc[m][n] = __builtin_amdgcn_mfma_f32_16x16x32_bf16(a[m], b[n], acc[m][n], 0, 0, 0);
  }

  #pragma unroll
  for (int m = 0; m < 4; m++) {
    int rl = (wr << 6) + m * 16 + ((lane >> 4) << 2);
    #pragma unroll
    for (int n = 0; n < 4; n++) {
      int cg = (wc << 6) + n * 16 + cfrag;
      #pragma unroll
      for (int j = 0; j < 4; j++) {
        int rg = n0 + rl + j;
        if (rg < NN) {
          float val = acc[m][n][j] + bn2L[cg];
          float o = (h[(size_t)rg * 256 + cg] + val) * nmask[rg];
          hout[(size_t)rg * 256 + cg] = o;
        }
      }
    }
  }
}

extern "C" void kernel_launch(void* const* d_in, const int* in_sizes, int n_in,
                              void* d_out, int out_size, void* d_ws, size_t ws_size,
                              hipStream_t stream) {
  (void)in_sizes; (void)n_in; (void)out_size; (void)ws_size;
  const float* h     = (const float*)d_in[0];
  const int*   eidx  = (const int*)d_in[1];
  const float* eattr = (const float*)d_in[2];
  const float* nmask = (const float*)d_in[3];
  const float* emask = (const float*)d_in[4];
  const float* We1 = (const float*)d_in[5];
  const float* be1 = (const float*)d_in[6];
  const float* We2 = (const float*)d_in[7];
  const float* be2 = (const float*)d_in[8];
  const float* Wa  = (const float*)d_in[9];
  const float* ba  = (const float*)d_in[10];
  const float* Wn1 = (const float*)d_in[11];
  const float* bn1 = (const float*)d_in[12];
  const float* Wn2 = (const float*)d_in[13];
  const float* bn2 = (const float*)d_in[14];

  char* ws = (char*)d_ws;
  unsigned short* We1T = (unsigned short*)(ws + 0);         // 278528 B
  unsigned short* We2T = (unsigned short*)(ws + 278528);    // 131072
  unsigned short* Wn1T = (unsigned short*)(ws + 409600);    // 262144
  unsigned short* Wn2T = (unsigned short*)(ws + 671744);    // 131072
  float* agg      = (float*)(ws + 802816);                  // 10,240,000
  float* attm     = (float*)(ws + 11042816);                // 1,280,000
  int*   counts   = (int*)(ws + 12322816);                  // 40,000
  int*   rowStart = (int*)(ws + 12362816);                  // 40,004 (pad to 8)
  int*   cursor   = (int*)(ws + 12402824);                  // 40,000
  int*   eorder   = (int*)(ws + 12442824);                  // 1,280,000
  int*   rowi     = (int*)(ws + 13722824);                  // 1,280,000

  float* hout = (float*)d_out;
  float* mij  = (float*)d_out + (size_t)NN * 256;

  hipMemsetAsync(counts, 0, NN * sizeof(int), stream);
  prep_kernel<<<1568, 256, 0, stream>>>(We1, We2, Wn1, Wn2, We1T, We2T, Wn1T, Wn2T);
  hist_kernel<<<(NE + 255) / 256, 256, 0, stream>>>(eidx, rowi, counts);
  scan_kernel<<<1, 1024, 0, stream>>>(counts, rowStart, cursor);
  scatter_kernel<<<(NE + 255) / 256, 256, 0, stream>>>(rowi, cursor, eorder);
  edge_kernel<<<NE / 128, 512, 0, stream>>>(h, eidx, eattr, emask, We1T, be1, We2T, be2,
                                            Wa, ba, mij, attm);
  agg_kernel<<<NN, 256, 0, stream>>>(mij, attm, rowStart, eorder, agg);
  node_kernel<<<(NN + 127) / 128, 512, 0, stream>>>(h, agg, nmask, Wn1T, bn1, Wn2T, bn2, hout);
}